// Round 1
// baseline (108.736 us; speedup 1.0000x reference)
//
#include <hip/hip_runtime.h>
#include <cstdint>
#include <cstddef>

// Problem constants (from reference): x[64][1024][32], W[1024][32], b[1024]
// out[64][1024][1024] f32
#define BATCH   64
#define SEQLEN  1024
#define KDIM    32
#define ODIM    1024

// ---------------------------------------------------------------------------
// Kernel 1: weight ternary quantization (BitNet b1.58).
// Single block, deterministic reduction of mean(|W|) over 32768 elements,
// then wq = clip(round(W*scale),-1,1)/scale stored TRANSPOSED: wT[k][o].
// ---------------------------------------------------------------------------
__global__ __launch_bounds__(1024) void quant_w_kernel(const float* __restrict__ W,
                                                       float* __restrict__ wT) {
    __shared__ float red[1024];
    __shared__ float s_scale;
    const int t = threadIdx.x;

    float acc = 0.f;
    #pragma unroll
    for (int j = 0; j < 32; ++j) acc += fabsf(W[t + j * 1024]);
    red[t] = acc;
    __syncthreads();
    for (int step = 512; step > 0; step >>= 1) {
        if (t < step) red[t] += red[t + step];
        __syncthreads();
    }
    if (t == 0) {
        float mean = red[0] * (1.0f / 32768.0f);
        s_scale = 1.0f / fmaxf(mean, 1e-5f);   // matches ref: scale = 1/clip(mean,1e-5)
    }
    __syncthreads();
    const float sc = s_scale;

    #pragma unroll
    for (int j = 0; j < 32; ++j) {
        int i = t + j * 1024;           // i = o*32 + k
        int o = i >> 5;
        int k = i & 31;
        float q = fminf(fmaxf(rintf(W[i] * sc), -1.0f), 1.0f);
        wT[k * ODIM + o] = q / sc;      // ref divides by scale
    }
}

// ---------------------------------------------------------------------------
// Kernel 2: per-token activation absmax quantization.
// One thread per element; absmax reduced across the 32 lanes of each token
// (tokens are 32-element contiguous rows, so lanes [0..31] / [32..63] of a
// wave each cover exactly one token).
// ---------------------------------------------------------------------------
__global__ __launch_bounds__(256) void quant_x_kernel(const float* __restrict__ x,
                                                      float* __restrict__ xq) {
    const int idx = blockIdx.x * 256 + threadIdx.x;
    float v = x[idx];
    float a = fabsf(v);
    #pragma unroll
    for (int off = 1; off < 32; off <<= 1)
        a = fmaxf(a, __shfl_xor(a, off, 32));
    float scale = 127.0f / fmaxf(a, 1e-5f);    // ref: 127/clip(absmax,1e-5)
    // |v*scale| <= 127 exactly, so the [-128,127] clip cannot bind.
    xq[idx] = rintf(v * scale) / scale;        // rintf == round-half-even == jnp.round
}

// ---------------------------------------------------------------------------
// Kernel 3: fused GEMV + bias + positional encoding.
// Grid: 1024 s-values x 2 column-chunks. Block 256 threads; each thread owns
// columns (o0, o0+1) -> 64 weight values in VGPRs. Inner loop over b reads the
// quantized x row through a wave-UNIFORM address (scalar loads) and issues
// pure v_fmac_f32. PE: pair (even o0, o0+1) shares one angle -> sin/cos once.
// ---------------------------------------------------------------------------
__global__ __launch_bounds__(256) void bitlinear_kernel(const float* __restrict__ xq,
                                                        const float* __restrict__ wT,
                                                        const float* __restrict__ bias,
                                                        float* __restrict__ out) {
    const int blk = blockIdx.x;
    const int s   = blk >> 1;
    const int oc  = blk & 1;
    const int o0  = oc * 512 + threadIdx.x * 2;   // even

    // Load the two weight columns (coalesced float2 across the wave).
    float w0[32], w1[32];
    const float2* wT2 = reinterpret_cast<const float2*>(wT);
    #pragma unroll
    for (int k = 0; k < 32; ++k) {
        float2 wv = wT2[(k * ODIM + o0) >> 1];
        w0[k] = wv.x;
        w1[k] = wv.y;
    }

    // bias + positional encoding (computed once; reused for all 64 batches)
    float add0, add1;
    {
        float bb0 = bias[o0];
        float bb1 = bias[o0 + 1];
        // even_i = o0 for both elements of the pair
        float inv   = powf(10000.0f, -(float)o0 * (1.0f / 1024.0f));
        float angle = (float)s * inv;
        add0 = bb0 + sinf(angle);   // even column -> sin
        add1 = bb1 + cosf(angle);   // odd  column -> cos
    }

    float2* outp = reinterpret_cast<float2*>(out + (size_t)s * ODIM + o0);
    const size_t out_stride_b = (size_t)SEQLEN * ODIM / 2;   // in float2 units

    for (int b = 0; b < BATCH; ++b) {
        // Wave-uniform address -> scalar (s_load) path
        const float4* xr = reinterpret_cast<const float4*>(
            xq + ((size_t)b * SEQLEN + s) * KDIM);
        float a0 = 0.f, a1 = 0.f;
        #pragma unroll
        for (int k4 = 0; k4 < 8; ++k4) {
            float4 xv = xr[k4];
            a0 = fmaf(xv.x, w0[4 * k4 + 0], a0);  a1 = fmaf(xv.x, w1[4 * k4 + 0], a1);
            a0 = fmaf(xv.y, w0[4 * k4 + 1], a0);  a1 = fmaf(xv.y, w1[4 * k4 + 1], a1);
            a0 = fmaf(xv.z, w0[4 * k4 + 2], a0);  a1 = fmaf(xv.z, w1[4 * k4 + 2], a1);
            a0 = fmaf(xv.w, w0[4 * k4 + 3], a0);  a1 = fmaf(xv.w, w1[4 * k4 + 3], a1);
        }
        float2 r;
        r.x = a0 + add0;
        r.y = a1 + add1;
        outp[(size_t)b * out_stride_b] = r;
    }
}

// ---------------------------------------------------------------------------
extern "C" void kernel_launch(void* const* d_in, const int* in_sizes, int n_in,
                              void* d_out, int out_size, void* d_ws, size_t ws_size,
                              hipStream_t stream) {
    const float* x = (const float*)d_in[0];   // [64][1024][32]
    const float* W = (const float*)d_in[1];   // [1024][32]
    const float* b = (const float*)d_in[2];   // [1024]
    float* out = (float*)d_out;               // [64][1024][1024]

    // Workspace layout: wT f32[32][1024] (128 KB) | xq f32[64][1024][32] (8 MB)
    float* wT = (float*)d_ws;
    float* xq = wT + KDIM * ODIM;

    quant_w_kernel<<<1, 1024, 0, stream>>>(W, wT);
    quant_x_kernel<<<(BATCH * SEQLEN * KDIM) / 256, 256, 0, stream>>>(x, xq);
    bitlinear_kernel<<<SEQLEN * 2, 256, 0, stream>>>(xq, wT, b, out);
}

// Round 2
// 79.138 us; speedup vs baseline: 1.3740x; 1.3740x over previous
//
#include <hip/hip_runtime.h>
#include <cstdint>
#include <cstddef>

// x[64][1024][32] f32, W[1024][32] f32, b[1024] f32 -> out[64][1024][1024] f32
#define BATCH   64
#define SEQLEN  1024
#define KDIM    32
#define ODIM    1024
#define NTOK    (BATCH * SEQLEN)          // 65536 tokens

typedef __attribute__((ext_vector_type(8))) short bf16x8;   // 8 bf16 = 4 VGPRs
typedef __attribute__((ext_vector_type(4))) float f32x4;

// exact f32 -> bf16 for values known exactly representable (ints <= 256, 0, +-1)
__device__ __forceinline__ unsigned short f32_to_bf16_exact(float f) {
    union { float f; unsigned int u; } cv; cv.f = f;
    return (unsigned short)(cv.u >> 16);
}

// ---------------------------------------------------------------------------
// Kernel 1: weight ternary quant -> wq bf16[o][k] (t in {-1,0,1}) + rw scalar.
// Single block, deterministic reduction. w_eff = t * rw, rw = clip(mean|W|,1e-5).
// ---------------------------------------------------------------------------
__global__ __launch_bounds__(1024) void quant_w_kernel(const float* __restrict__ W,
                                                       unsigned short* __restrict__ wq,
                                                       float* __restrict__ rw_out) {
    __shared__ float red[1024];
    __shared__ float s_sc;
    const int t = threadIdx.x;            // thread t owns row o = t (32 elems)

    float4 wv[8];
    const float4* W4 = reinterpret_cast<const float4*>(W + t * KDIM);
    float acc = 0.f;
    #pragma unroll
    for (int j = 0; j < 8; ++j) {
        wv[j] = W4[j];
        acc += fabsf(wv[j].x) + fabsf(wv[j].y) + fabsf(wv[j].z) + fabsf(wv[j].w);
    }
    red[t] = acc;
    __syncthreads();
    for (int step = 512; step > 0; step >>= 1) {
        if (t < step) red[t] += red[t + step];
        __syncthreads();
    }
    if (t == 0) {
        float mean = red[0] * (1.0f / 32768.0f);
        s_sc = 1.0f / fmaxf(mean, 1e-5f);            // scale
        rw_out[0] = fmaxf(mean, 1e-5f);              // 1/scale
    }
    __syncthreads();
    const float sc = s_sc;

    unsigned short* row = wq + t * KDIM;
    #pragma unroll
    for (int j = 0; j < 8; ++j) {
        float e[4] = {wv[j].x, wv[j].y, wv[j].z, wv[j].w};
        #pragma unroll
        for (int c = 0; c < 4; ++c) {
            float q = fminf(fmaxf(rintf(e[c] * sc), -1.0f), 1.0f);  // ternary
            row[j * 4 + c] = f32_to_bf16_exact(q);
        }
    }
}

// ---------------------------------------------------------------------------
// Kernel 2: activation quant -> xq bf16[token][k] holding INTEGER n in
// [-127,127], plus rx[token] = clip(absmax,1e-5)/127 (the 1/scale factor).
// ---------------------------------------------------------------------------
__global__ __launch_bounds__(256) void quant_x_kernel(const float* __restrict__ x,
                                                      unsigned short* __restrict__ xq,
                                                      float* __restrict__ rx) {
    const int idx = blockIdx.x * 256 + threadIdx.x;
    float v = x[idx];
    float a = fabsf(v);
    #pragma unroll
    for (int off = 1; off < 32; off <<= 1)
        a = fmaxf(a, __shfl_xor(a, off, 32));
    float am = fmaxf(a, 1e-5f);
    float scale = 127.0f / am;                  // |v*scale| <= 127: clip can't bind
    float n = rintf(v * scale);                 // round-half-even == jnp.round
    xq[idx] = f32_to_bf16_exact(n);             // ints <=127: exact in bf16
    if ((idx & 31) == 0) rx[idx >> 5] = am * (1.0f / 127.0f);
}

// ---------------------------------------------------------------------------
// Kernel 3: add-table  add[s][o] = f32(pe_f64(s,o)) + bias[o]   (4 MB)
// f64 pow/sin/cos matches the numpy float64 reference to the f32 cast.
// ---------------------------------------------------------------------------
__global__ __launch_bounds__(256) void pe_bias_kernel(const float* __restrict__ bias,
                                                      float* __restrict__ add) {
    const int idx = blockIdx.x * 256 + threadIdx.x;   // s*1024 + o
    const int o = idx & (ODIM - 1);
    const int s = idx >> 10;
    const double even = (double)(o & ~1);
    // 10000^(-even/1024) = exp2(log2(10000) * (-even/1024))
    const double inv = exp2(-13.287712379549449 * (even * (1.0 / 1024.0)));
    const double ang = (double)s * inv;
    float pe = (float)((o & 1) ? cos(ang) : sin(ang));
    add[idx] = pe + bias[o];
}

// ---------------------------------------------------------------------------
// Kernel 4: store-bound MFMA GEMM + epilogue.
// D(M=o 16, N=token 16, K=32) = wq . xq^T  via one mfma_f32_16x16x32_bf16.
// Block: 4 waves, tile = 16 s x 64 o, b split 4 waves x 16.
// Grid: 64 s-blocks x 16 o-blocks = 1024 blocks.
// Fragment maps (guide-verified): A row=lane&15,k=(lane>>4)*8+j;
// B col=lane&15,k=(lane>>4)*8+j; D col=lane&15(token), row=(lane>>4)*4+reg (o)
// -> per-lane float4 store of 4 consecutive o at one token.
// ---------------------------------------------------------------------------
__global__ __launch_bounds__(256) void bitgemm_kernel(
    const unsigned short* __restrict__ xq,   // [65536][32] bf16 (int n)
    const float*  __restrict__ rx,           // [65536]
    const unsigned short* __restrict__ wq,   // [1024][32] bf16 (ternary)
    const float*  __restrict__ rwp,          // [1]
    const float*  __restrict__ add,          // [1024][1024] bias+pe
    float* __restrict__ out)                 // [65536][1024]
{
    const int lane = threadIdx.x & 63;
    const int wid  = threadIdx.x >> 6;
    const int l15  = lane & 15;
    const int hi   = lane >> 4;              // 0..3

    const int oblk = blockIdx.x & 15;
    const int sblk = blockIdx.x >> 4;
    const int o0   = oblk * 64;
    const int s0   = sblk * 16;

    const float rw = rwp[0];

    // A fragments (weights), hoisted: wq[o0 + f*16 + l15][hi*8 .. +8]
    bf16x8 afrag[4];
    #pragma unroll
    for (int f = 0; f < 4; ++f)
        afrag[f] = *reinterpret_cast<const bf16x8*>(
            wq + (size_t)(o0 + f * 16 + l15) * KDIM + hi * 8);

    // bias+pe fragments, hoisted: add[s0 + l15][o0 + f*16 + hi*4 .. +4]
    f32x4 addf[4];
    #pragma unroll
    for (int f = 0; f < 4; ++f)
        addf[f] = *reinterpret_cast<const f32x4*>(
            add + (size_t)(s0 + l15) * ODIM + o0 + f * 16 + hi * 4);

    // b-loop: wave wid covers b = wid*16 .. wid*16+15
    for (int i = 0; i < 16; ++i) {
        const int b    = wid * 16 + i;
        const int tok0 = b * SEQLEN + s0;           // token col = tok0 + l15

        // B fragment: xq[tok0 + l15][hi*8 .. +8] — 1 KB contiguous per wave
        bf16x8 bfrag = *reinterpret_cast<const bf16x8*>(
            xq + (size_t)(tok0 + l15) * KDIM + hi * 8);
        const float rxw = rx[tok0 + l15] * rw;      // combined scale (per token)

        f32x4 acc[4];
        #pragma unroll
        for (int f = 0; f < 4; ++f) {
            acc[f] = (f32x4){0.f, 0.f, 0.f, 0.f};
            acc[f] = __builtin_amdgcn_mfma_f32_16x16x32_bf16(afrag[f], bfrag, acc[f], 0, 0, 0);
        }

        float* op = out + (size_t)(tok0 + l15) * ODIM + o0 + hi * 4;
        #pragma unroll
        for (int f = 0; f < 4; ++f) {
            f32x4 r;
            #pragma unroll
            for (int j = 0; j < 4; ++j)
                r[j] = fmaf(acc[f][j], rxw, addf[f][j]);
            *reinterpret_cast<f32x4*>(op + f * 16) = r;   // dwordx4 store
        }
    }
}

// ---------------------------------------------------------------------------
extern "C" void kernel_launch(void* const* d_in, const int* in_sizes, int n_in,
                              void* d_out, int out_size, void* d_ws, size_t ws_size,
                              hipStream_t stream) {
    const float* x = (const float*)d_in[0];   // [64][1024][32]
    const float* W = (const float*)d_in[1];   // [1024][32]
    const float* b = (const float*)d_in[2];   // [1024]
    float* out = (float*)d_out;

    // ws layout (16B-aligned slices):
    //   xq  bf16[65536][32]   4 MB   @ 0
    //   add f32 [1024][1024]  4 MB   @ 4 MB
    //   rx  f32 [65536]     256 KB   @ 8 MB
    //   wq  bf16[1024][32]   64 KB   @ 8 MB + 256 KB
    //   rw  f32 [1]                  @ 8 MB + 320 KB
    char* wsb = (char*)d_ws;
    unsigned short* xq = (unsigned short*)(wsb);
    float*          add = (float*)(wsb + (4u << 20));
    float*          rx  = (float*)(wsb + (8u << 20));
    unsigned short* wq  = (unsigned short*)(wsb + (8u << 20) + (256u << 10));
    float*          rw  = (float*)(wsb + (8u << 20) + (320u << 10));

    quant_w_kernel<<<1, 1024, 0, stream>>>(W, wq, rw);
    quant_x_kernel<<<(NTOK * KDIM) / 256, 256, 0, stream>>>(x, xq, rx);
    pe_bias_kernel<<<(SEQLEN * ODIM) / 256, 256, 0, stream>>>(b, add);
    bitgemm_kernel<<<64 * 16, 256, 0, stream>>>(xq, rx, wq, rw, add, out);
}